// Round 1
// baseline (1961.664 us; speedup 1.0000x reference)
//
#include <hip/hip_runtime.h>
#include <hip/hip_bf16.h>
#include <stdint.h>
#include <math.h>

typedef __hip_bfloat16 bf16;
typedef __attribute__((ext_vector_type(4))) float floatx4;
typedef __attribute__((ext_vector_type(8))) __bf16 bf16x8;

typedef __attribute__((address_space(1))) void gvoid_t;
typedef __attribute__((address_space(3))) void lvoid_t;

__device__ __forceinline__ void gl_lds16(const void* g, void* l){
  __builtin_amdgcn_global_load_lds((gvoid_t*)g, (lvoid_t*)l, 16, 0, 0);
}

__device__ __forceinline__ float gelu_f(float v){
  // 0.5*v*(1+tanh(sqrt(2/pi)*(v+0.044715 v^3))) == v*e/(e+1), e=exp(2u)
  float u = 0.7978845608028654f*(v + 0.044715f*v*v*v);
  float e = __expf(2.0f*u);
  return v*(1.0f - 1.0f/(e+1.0f));
}

// ---------------- GEMM: C[M,N] = A[M,K](bf16) @ B (given as BT[N,K] bf16) + bias ----------
// MODE 0: bf16 C = acc+bias
// MODE 1: bf16 C = gelu(acc+bias)
// MODE 2: f32  C = acc+bias + addend[(row&addmask)*N + col]
// M multiple of 128 (grid.y), N multiple of 128 (grid.x), K multiple of 32. No bounds checks.
template<int MODE>
__global__ __launch_bounds__(256,2)
void gemm_bf16(const bf16* __restrict__ A, const bf16* __restrict__ BT,
               const float* __restrict__ bias, void* __restrict__ C,
               const float* __restrict__ addend, unsigned addmask,
               int N, int K)
{
  __shared__ bf16 As[128*32];
  __shared__ bf16 Bs[128*32];
  const int tid  = threadIdx.x;
  const int wave = tid>>6, lane = tid&63;
  const int quad = lane>>4, l16 = lane&15;
  const int m0 = blockIdx.y*128, n0 = blockIdx.x*128;
  const int wm = (wave&1)*64, wn = (wave>>1)*64;
  floatx4 acc[4][4] = {};
  // staging: seg s (0..7) covers 16 rows; wave handles segs {2w,2w+1}; lane -> row lane>>2, 16B col (lane&3)
  const bf16* ag = A  + (size_t)(m0 + wave*32 + (lane>>2))*K + (lane&3)*8;
  const bf16* bg = BT + (size_t)(n0 + wave*32 + (lane>>2))*K + (lane&3)*8;
  bf16* asl = As + wave*1024;
  bf16* bsl = Bs + wave*1024;
  const size_t row16 = (size_t)16*K;
  for (int k0=0; k0<K; k0+=32){
    __syncthreads();
    gl_lds16(ag + k0,          asl);
    gl_lds16(ag + k0 + row16,  asl + 512);
    gl_lds16(bg + k0,          bsl);
    gl_lds16(bg + k0 + row16,  bsl + 512);
    __syncthreads();
    bf16x8 af[4], bfr[4];
#pragma unroll
    for (int i=0;i<4;i++) af[i]  = *(const bf16x8*)(As + (wm + i*16 + l16)*32 + quad*8);
#pragma unroll
    for (int j=0;j<4;j++) bfr[j] = *(const bf16x8*)(Bs + (wn + j*16 + l16)*32 + quad*8);
#pragma unroll
    for (int i=0;i<4;i++)
#pragma unroll
      for (int j=0;j<4;j++)
        acc[i][j] = __builtin_amdgcn_mfma_f32_16x16x32_bf16(af[i], bfr[j], acc[i][j], 0,0,0);
  }
  // epilogue: C/D layout col=lane&15, row=quad*4+reg (m89-verified)
#pragma unroll
  for (int i=0;i<4;i++){
    const int gr0 = m0 + wm + i*16 + quad*4;
#pragma unroll
    for (int j=0;j<4;j++){
      const int gc = n0 + wn + j*16 + l16;
      const float bv = bias[gc];
#pragma unroll
      for (int r=0;r<4;r++){
        const int gr = gr0 + r;
        float v = acc[i][j][r] + bv;
        if constexpr (MODE==1) v = gelu_f(v);
        if constexpr (MODE==2){
          ((float*)C)[(size_t)gr*N + gc] = v + addend[(size_t)(gr & addmask)*N + gc];
        } else {
          ((bf16*)C)[(size_t)gr*N + gc] = __float2bfloat16(v);
        }
      }
    }
  }
}

// ---------------- LayerNorm over D=1152, one wave per row ----------------
template<int OUTF32>
__global__ __launch_bounds__(256)
void ln_kernel(const float* __restrict__ x, const float* __restrict__ g,
               const float* __restrict__ b, void* __restrict__ out)
{
  const int row  = blockIdx.x*4 + (threadIdx.x>>6);
  const int lane = threadIdx.x & 63;
  const float2* xr = (const float2*)(x + (size_t)row*1152);
  float2 v[9]; float s=0.f, ss=0.f;
#pragma unroll
  for (int r=0;r<9;r++){
    v[r] = xr[r*64+lane];
    s  += v[r].x + v[r].y;
    ss += v[r].x*v[r].x + v[r].y*v[r].y;
  }
#pragma unroll
  for (int m=1;m<64;m<<=1){ s += __shfl_xor(s,m,64); ss += __shfl_xor(ss,m,64); }
  const float mean = s*(1.0f/1152.0f);
  const float rs = rsqrtf(ss*(1.0f/1152.0f) - mean*mean + 1e-6f);
  const float2* gr2 = (const float2*)g;
  const float2* br2 = (const float2*)b;
#pragma unroll
  for (int r=0;r<9;r++){
    const int c = r*64+lane;
    const float2 gg = gr2[c], bb = br2[c];
    const float o0 = (v[r].x-mean)*rs*gg.x + bb.x;
    const float o1 = (v[r].y-mean)*rs*gg.y + bb.y;
    if constexpr (OUTF32){
      ((float2*)out)[(size_t)row*576 + c] = make_float2(o0, o1);
    } else {
      __hip_bfloat162 hv;
      hv.x = __float2bfloat16(o0); hv.y = __float2bfloat16(o1);
      ((__hip_bfloat162*)out)[(size_t)row*576 + c] = hv;
    }
  }
}

// ---------------- im2col for 14x14 stride-14 conv: [4096, 608] bf16, pad 588..607 = 0 ----
__global__ __launch_bounds__(256)
void im2col_kernel(const float* __restrict__ img, bf16* __restrict__ out)
{
  const int idx = blockIdx.x*256 + threadIdx.x;  // 4096*608
  const int kk = idx % 608;
  const int rr = idx / 608;
  float v = 0.f;
  if (kk < 588){
    const int bt = rr >> 10, n = rr & 1023;
    const int py = n >> 5, px = n & 31;
    const int ph = kk / 42;
    const int rem = kk - ph*42;
    const int pw = rem / 3;
    const int c  = rem - pw*3;
    v = img[(((size_t)bt*448 + py*14 + ph)*448 + px*14 + pw)*3 + c];
  }
  out[idx] = __float2bfloat16(v);
}

// ---------------- fp32 [K,N] -> bf16 [Np,Kp] transpose+convert, zero-pad -----------------
__global__ __launch_bounds__(256)
void transpose_cvt(const float* __restrict__ in, bf16* __restrict__ out,
                   int K, int N, int Kp, int Np)
{
  __shared__ float tile[32][33];
  const int nt = blockIdx.x*32, kt = blockIdx.y*32;
  const int r = threadIdx.x>>5, c = threadIdx.x&31;
#pragma unroll
  for (int i=0;i<4;i++){
    const int k = kt + r + i*8, n = nt + c;
    tile[r+i*8][c] = (k<K && n<N) ? in[(size_t)k*N + n] : 0.f;
  }
  __syncthreads();
#pragma unroll
  for (int i=0;i<4;i++){
    const int n = nt + r + i*8, k = kt + c;
    out[(size_t)n*Kp + k] = __float2bfloat16(tile[c][r+i*8]);
  }
}

// ---------------- bias packing: [bq|bk|bv] -> [3456], b1 -> [4352] padded ---------------
__global__ __launch_bounds__(256)
void pack_biases(const float* __restrict__ bq, const float* __restrict__ bk,
                 const float* __restrict__ bv, const float* __restrict__ b1,
                 int l, float* __restrict__ bqkv, float* __restrict__ b1p)
{
  const int i = blockIdx.x*256 + threadIdx.x;
  if (i < 3456){
    float v;
    if (i < 1152)      v = bq[l*1152 + i];
    else if (i < 2304) v = bk[l*1152 + i - 1152];
    else               v = bv[l*1152 + i - 2304];
    bqkv[i] = v;
  }
  if (i < 4352) b1p[i] = (i < 4304) ? b1[l*4304 + i] : 0.f;
}

// -------- q/k repack: qkv_raw[4096,3456] col block -> [64 bh][1024 n][96 dh] (pad 0) -----
__global__ __launch_bounds__(256)
void repack_qk(const bf16* __restrict__ src, bf16* __restrict__ dst, float scale, int col0)
{
  const int idx = blockIdx.x*256 + threadIdx.x;   // 64*1024*96
  const int dh = idx % 96;
  const int t  = idx / 96;
  const int n  = t & 1023;
  const int bh = t >> 10;
  const int hh = bh & 15, bt = bh >> 4;
  float v = 0.f;
  if (dh < 72) v = __bfloat162float(src[((size_t)bt*1024 + n)*3456 + col0 + hh*72 + dh]) * scale;
  dst[idx] = __float2bfloat16(v);
}

// -------- v repack transposed: qkv_raw v-cols -> [64 bh][80 dh][1024 n] (pad rows 0) -----
__global__ __launch_bounds__(256)
void transpose_v(const bf16* __restrict__ src, bf16* __restrict__ dst)
{
  __shared__ bf16 tile[128][73];
  const int nc = blockIdx.x, bh = blockIdx.y;
  const int bt = bh>>4, hh = bh&15;
  const bf16* s = src + ((size_t)bt*1024 + nc*128)*3456 + 2304 + hh*72;
  for (int e=threadIdx.x; e<128*72; e+=256){
    const int n = e/72, dh = e - n*72;
    tile[n][dh] = s[(size_t)n*3456 + dh];
  }
  __syncthreads();
  bf16* d = dst + (size_t)bh*80*1024 + nc*128;
  const bf16 z = __float2bfloat16(0.f);
  for (int e=threadIdx.x; e<80*128; e+=256){
    const int dh = e>>7, n = e&127;
    d[(size_t)dh*1024 + n] = (dh<72) ? tile[n][dh] : z;
  }
}

// ---------------- flash attention: block = (bt,h, 64-query tile), chunks of 128 keys ------
// q/k: [64 bh][1024][96] (q pre-scaled by 1/sqrt(72)*log2(e)); v: [64 bh][80][1024]
__global__ __launch_bounds__(256,2)
void attn_kernel(const bf16* __restrict__ qb, const bf16* __restrict__ kb,
                 const bf16* __restrict__ vb, bf16* __restrict__ outp)
{
  __shared__ bf16 Ks[128*96];   // 24576 B
  __shared__ bf16 Vs[80*128];   // 20480 B
  __shared__ bf16 Ps[64*136];   // 17408 B  (stride 136 for 16B-aligned b128 reads)
  const int tid = threadIdx.x, wave = tid>>6, lane = tid&63;
  const int quad = lane>>4, l16 = lane&15;
  const int bh = blockIdx.y, q0 = blockIdx.x*64;
  const bf16* kg = kb + (size_t)bh*1024*96;
  const bf16* vg = vb + (size_t)bh*80*1024;
  // Q fragments in registers (wave owns q-rows wave*16..+15)
  const bf16* qrow = qb + ((size_t)bh*1024 + q0 + wave*16 + l16)*96 + quad*8;
  const bf16x8 af0 = *(const bf16x8*)(qrow);
  const bf16x8 af1 = *(const bf16x8*)(qrow+32);
  const bf16x8 af2 = *(const bf16x8*)(qrow+64);
  float mr[4], lr[4];
#pragma unroll
  for (int r=0;r<4;r++){ mr[r] = -3.0e38f; lr[r] = 0.f; }
  floatx4 oacc[5] = {};
  for (int kc=0;kc<8;kc++){
    __syncthreads();   // prev chunk's reads of Ks/Vs/Ps complete
    {
      const char* kcb = (const char*)kg + kc*24576;
#pragma unroll
      for (int i=0;i<6;i++){
        const int sgi = wave*6+i;
        gl_lds16(kcb + sgi*1024 + lane*16, (char*)Ks + sgi*1024);
      }
#pragma unroll
      for (int i=0;i<5;i++){
        const int sgi = wave*5+i;
        gl_lds16((const char*)vg + (size_t)(sgi*4 + (lane>>4))*2048 + kc*256 + (lane&15)*16,
                 (char*)Vs + sgi*1024);
      }
    }
    __syncthreads();   // staging visible
    // S = Q K^T for this wave's 16 q-rows x 128 keys
    floatx4 sc[8] = {};
#pragma unroll
    for (int ct=0;ct<8;ct++){
      const bf16* kr = Ks + (ct*16+l16)*96 + quad*8;
      sc[ct] = __builtin_amdgcn_mfma_f32_16x16x32_bf16(af0, *(const bf16x8*)(kr   ), sc[ct],0,0,0);
      sc[ct] = __builtin_amdgcn_mfma_f32_16x16x32_bf16(af1, *(const bf16x8*)(kr+32), sc[ct],0,0,0);
      sc[ct] = __builtin_amdgcn_mfma_f32_16x16x32_bf16(af2, *(const bf16x8*)(kr+64), sc[ct],0,0,0);
    }
    // online softmax in registers; row = wave*16 + quad*4 + r, col = l16 (per col-tile)
    float cm[4];
#pragma unroll
    for (int r=0;r<4;r++){
      cm[r] = sc[0][r];
#pragma unroll
      for (int ct=1;ct<8;ct++) cm[r] = fmaxf(cm[r], sc[ct][r]);
    }
#pragma unroll
    for (int off=1; off<16; off<<=1)
#pragma unroll
      for (int r=0;r<4;r++) cm[r] = fmaxf(cm[r], __shfl_xor(cm[r], off, 64));
    float al[4], ls[4];
#pragma unroll
    for (int r=0;r<4;r++){
      const float mn = fmaxf(mr[r], cm[r]);
      al[r] = exp2f(mr[r]-mn);
      mr[r] = mn; ls[r] = 0.f;
    }
#pragma unroll
    for (int ct=0;ct<8;ct++){
#pragma unroll
      for (int r=0;r<4;r++){
        const float pv = exp2f(sc[ct][r]-mr[r]);
        ls[r] += pv;
        Ps[(wave*16+quad*4+r)*136 + ct*16+l16] = __float2bfloat16(pv);
      }
    }
#pragma unroll
    for (int off=1; off<16; off<<=1)
#pragma unroll
      for (int r=0;r<4;r++) ls[r] += __shfl_xor(ls[r], off, 64);
#pragma unroll
    for (int r=0;r<4;r++) lr[r] = lr[r]*al[r] + ls[r];
#pragma unroll
    for (int t=0;t<5;t++)
#pragma unroll
      for (int r=0;r<4;r++) oacc[t][r] *= al[r];
    __syncthreads();   // Ps writes visible
    // O += P @ V   (A = Ps rows wave*16.., B^T = Vs[dh][key])
#pragma unroll
    for (int ks=0;ks<4;ks++){
      const bf16x8 pf = *(const bf16x8*)(Ps + (wave*16+l16)*136 + ks*32 + quad*8);
#pragma unroll
      for (int t=0;t<5;t++){
        const bf16x8 vf = *(const bf16x8*)(Vs + (t*16+l16)*128 + ks*32 + quad*8);
        oacc[t] = __builtin_amdgcn_mfma_f32_16x16x32_bf16(pf, vf, oacc[t],0,0,0);
      }
    }
  }
  const int bt = bh>>4, hh = bh&15;
#pragma unroll
  for (int t=0;t<5;t++){
    const int dh = t*16+l16;
    if (dh < 72){
#pragma unroll
      for (int r=0;r<4;r++){
        const int q = wave*16 + quad*4 + r;
        const float v = oacc[t][r] / lr[r];
        outp[((size_t)bt*1024 + q0 + q)*1152 + hh*72 + dh] = __float2bfloat16(v);
      }
    }
  }
}

extern "C" void kernel_launch(void* const* d_in, const int* in_sizes, int n_in,
                              void* d_out, int out_size, void* d_ws, size_t ws_size,
                              hipStream_t stream)
{
  (void)in_sizes; (void)n_in; (void)out_size; (void)ws_size;
  const float* images = (const float*)d_in[0];
  const float* conv_w = (const float*)d_in[1];
  const float* conv_b = (const float*)d_in[2];
  const float* pos_emb= (const float*)d_in[3];
  const float* ln1_g  = (const float*)d_in[4];
  const float* ln1_b  = (const float*)d_in[5];
  const float* Wq     = (const float*)d_in[6];
  const float* bq     = (const float*)d_in[7];
  const float* Wk     = (const float*)d_in[8];
  const float* bk     = (const float*)d_in[9];
  const float* Wv     = (const float*)d_in[10];
  const float* bv     = (const float*)d_in[11];
  const float* Wo     = (const float*)d_in[12];
  const float* bo     = (const float*)d_in[13];
  const float* ln2_g  = (const float*)d_in[14];
  const float* ln2_b  = (const float*)d_in[15];
  const float* W1     = (const float*)d_in[16];
  const float* b1     = (const float*)d_in[17];
  const float* W2     = (const float*)d_in[18];
  const float* b2     = (const float*)d_in[19];
  const float* lnf_g  = (const float*)d_in[20];
  const float* lnf_b  = (const float*)d_in[21];

  char* p = (char*)d_ws;
  auto take = [&](size_t nbytes)->char*{ char* q = p; p += (nbytes + 255) & ~(size_t)255; return q; };
  float* xw   = (float*)take(4096ull*1152*4);   // fp32 residual stream
  bf16* hbuf  = (bf16*) take(4096ull*1152*2);   // post-LN bf16
  bf16* h1    = (bf16*) take(4096ull*4352*2);   // MLP intermediate (padded)
  bf16* qkvr  = h1;                              // alias: qkv raw gemm out, dead before h1 written
  bf16* qbuf  = (bf16*) take(64ull*1024*96*2);
  bf16* imcol = qbuf;                            // alias: im2col dead before layer-0 repack
  bf16* kbuf  = (bf16*) take(64ull*1024*96*2);
  bf16* vbuf  = (bf16*) take(64ull*80*1024*2);
  bf16* aout  = (bf16*) take(4096ull*1152*2);
  bf16* WqkvT = (bf16*) take(3456ull*1152*2);
  bf16* WoT   = (bf16*) take(1152ull*1152*2);
  bf16* W1T   = (bf16*) take(4352ull*1152*2);
  bf16* cwT   = W1T;                             // alias: conv weight dead before layer-0 W1T cvt
  bf16* W2T   = (bf16*) take(1152ull*4352*2);
  float* bqkv = (float*)take(3456*4);
  float* b1p  = (float*)take(4352*4);

  const float qscale = 1.4426950408889634f / sqrtf(72.0f);  // fold log2(e) into softmax scale

  // patch embedding: im2col GEMM, epilogue adds conv_b + pos_emb, writes fp32 residual
  im2col_kernel<<<9728, 256, 0, stream>>>(images, imcol);
  transpose_cvt<<<dim3(36,19), 256, 0, stream>>>(conv_w, cwT, 588, 1152, 608, 1152);
  gemm_bf16<2><<<dim3(9,32), 256, 0, stream>>>(imcol, cwT, conv_b, xw, pos_emb, 1023u, 1152, 608);

  for (int l=0;l<4;l++){
    // per-layer weight convert+transpose into reusable bf16 buffers
    transpose_cvt<<<dim3(36,36), 256, 0, stream>>>(Wq + (size_t)l*1152*1152, WqkvT,                1152,1152,1152,1152);
    transpose_cvt<<<dim3(36,36), 256, 0, stream>>>(Wk + (size_t)l*1152*1152, WqkvT + 1152ull*1152, 1152,1152,1152,1152);
    transpose_cvt<<<dim3(36,36), 256, 0, stream>>>(Wv + (size_t)l*1152*1152, WqkvT + 2304ull*1152, 1152,1152,1152,1152);
    transpose_cvt<<<dim3(36,36), 256, 0, stream>>>(Wo + (size_t)l*1152*1152, WoT, 1152,1152,1152,1152);
    transpose_cvt<<<dim3(136,36),256, 0, stream>>>(W1 + (size_t)l*1152*4304, W1T, 1152,4304,1152,4352);
    transpose_cvt<<<dim3(36,136),256, 0, stream>>>(W2 + (size_t)l*4304*1152, W2T, 4304,1152,4352,1152);
    pack_biases<<<17,256,0,stream>>>(bq,bk,bv,b1,l,bqkv,b1p);

    ln_kernel<0><<<1024,256,0,stream>>>(xw, ln1_g + l*1152, ln1_b + l*1152, hbuf);
    gemm_bf16<0><<<dim3(27,32),256,0,stream>>>(hbuf, WqkvT, bqkv, qkvr, nullptr, 0u, 3456, 1152);
    repack_qk<<<24576,256,0,stream>>>(qkvr, qbuf, qscale, 0);
    repack_qk<<<24576,256,0,stream>>>(qkvr, kbuf, 1.0f, 1152);
    transpose_v<<<dim3(8,64),256,0,stream>>>(qkvr, vbuf);
    attn_kernel<<<dim3(16,64),256,0,stream>>>(qbuf, kbuf, vbuf, aout);
    gemm_bf16<2><<<dim3(9,32),256,0,stream>>>(aout, WoT, bo + l*1152, xw, xw, 4095u, 1152, 1152);

    ln_kernel<0><<<1024,256,0,stream>>>(xw, ln2_g + l*1152, ln2_b + l*1152, hbuf);
    gemm_bf16<1><<<dim3(34,32),256,0,stream>>>(hbuf, W1T, b1p, h1, nullptr, 0u, 4352, 1152);
    gemm_bf16<2><<<dim3(9,32),256,0,stream>>>(h1, W2T, b2 + l*1152, xw, xw, 4095u, 1152, 4352);
  }
  ln_kernel<1><<<1024,256,0,stream>>>(xw, lnf_g, lnf_b, (float*)d_out);
}

// Round 2
// 1898.391 us; speedup vs baseline: 1.0333x; 1.0333x over previous
//
#include <hip/hip_runtime.h>
#include <hip/hip_bf16.h>
#include <stdint.h>
#include <math.h>

typedef __hip_bfloat16 bf16;
typedef __attribute__((ext_vector_type(4))) float floatx4;
typedef __attribute__((ext_vector_type(8))) __bf16 bf16x8;

typedef __attribute__((address_space(1))) void gvoid_t;
typedef __attribute__((address_space(3))) void lvoid_t;

__device__ __forceinline__ void gl_lds16(const void* g, void* l){
  __builtin_amdgcn_global_load_lds((gvoid_t*)g, (lvoid_t*)l, 16, 0, 0);
}

__device__ __forceinline__ float gelu_f(float v){
  float u = 0.7978845608028654f*(v + 0.044715f*v*v*v);
  float e = __expf(2.0f*u);
  return v*(1.0f - 1.0f/(e+1.0f));
}

// ---------------- GEMM: C[M,N] = A[M,K](bf16) @ BT[N,K](bf16) + bias ----------
// MODE 0: bf16 C = acc+bias
// MODE 1: bf16 C = gelu(acc+bias)
// MODE 3: bf16 C = (acc+bias) * (n0<1152 ? qs : 1)   [QKV with folded q-scale]
// MODE 4: f32 partial C[s][M][N] = acc + (s==0 ? bias : 0)   [split-K, blockIdx.z = s]
template<int MODE>
__global__ __launch_bounds__(256,2)
void gemm_bf16(const bf16* __restrict__ A, const bf16* __restrict__ BT,
               const float* __restrict__ bias, void* __restrict__ C,
               int N, int K, int kc, float qs)
{
  __shared__ bf16 As[128*32];
  __shared__ bf16 Bs[128*32];
  const int tid  = threadIdx.x;
  const int wave = tid>>6, lane = tid&63;
  const int quad = lane>>4, l16 = lane&15;
  const int m0 = blockIdx.y*128, n0 = blockIdx.x*128;
  const int s  = blockIdx.z;
  const int kb = s*kc;
  const int ke = min(K, kb + kc);
  const int wm = (wave&1)*64, wn = (wave>>1)*64;
  floatx4 acc[4][4] = {};
  const bf16* ag = A  + (size_t)(m0 + wave*32 + (lane>>2))*K + (lane&3)*8;
  const bf16* bg = BT + (size_t)(n0 + wave*32 + (lane>>2))*K + (lane&3)*8;
  bf16* asl = As + wave*1024;
  bf16* bsl = Bs + wave*1024;
  const size_t row16 = (size_t)16*K;
  for (int k0=kb; k0<ke; k0+=32){
    __syncthreads();
    gl_lds16(ag + k0,          asl);
    gl_lds16(ag + k0 + row16,  asl + 512);
    gl_lds16(bg + k0,          bsl);
    gl_lds16(bg + k0 + row16,  bsl + 512);
    __syncthreads();
    bf16x8 af[4], bfr[4];
#pragma unroll
    for (int i=0;i<4;i++) af[i]  = *(const bf16x8*)(As + (wm + i*16 + l16)*32 + quad*8);
#pragma unroll
    for (int j=0;j<4;j++) bfr[j] = *(const bf16x8*)(Bs + (wn + j*16 + l16)*32 + quad*8);
#pragma unroll
    for (int i=0;i<4;i++)
#pragma unroll
      for (int j=0;j<4;j++)
        acc[i][j] = __builtin_amdgcn_mfma_f32_16x16x32_bf16(af[i], bfr[j], acc[i][j], 0,0,0);
  }
  const float scale = (MODE==3 && n0<1152) ? qs : 1.0f;
#pragma unroll
  for (int i=0;i<4;i++){
    const int gr0 = m0 + wm + i*16 + quad*4;
#pragma unroll
    for (int j=0;j<4;j++){
      const int gc = n0 + wn + j*16 + l16;
      const float bv = (MODE!=4 || s==0) ? bias[gc] : 0.f;
#pragma unroll
      for (int r=0;r<4;r++){
        const int gr = gr0 + r;
        float v = acc[i][j][r] + bv;
        if constexpr (MODE==1) v = gelu_f(v);
        if constexpr (MODE==3) v *= scale;
        if constexpr (MODE==4){
          ((float*)C)[((size_t)s*4096 + gr)*N + gc] = v;
        } else {
          ((bf16*)C)[(size_t)gr*N + gc] = __float2bfloat16(v);
        }
      }
    }
  }
}

// ---------------- fused split-K reduce + residual + LayerNorm ----------------
// x_row = base[(row&bmask)] + sum_{s<ks} part[s][row]; if WRITEX: xw[row]=x_row;
// out[row] = LN(x_row)*g + b  (bf16 if !OUTF32 else f32)
template<int OUTF32, int WRITEX>
__global__ __launch_bounds__(256)
void ln_red(const float* __restrict__ base, unsigned bmask,
            const float* __restrict__ part, int ks,
            const float* __restrict__ g, const float* __restrict__ b,
            float* __restrict__ xw, void* __restrict__ out)
{
  const int row  = blockIdx.x*4 + (threadIdx.x>>6);
  const int lane = threadIdx.x & 63;
  const float2* br = (const float2*)base + (size_t)(row & bmask)*576;
  float2 v[9];
#pragma unroll
  for (int r=0;r<9;r++) v[r] = br[r*64+lane];
  for (int s=0;s<ks;s++){
    const float2* pr = (const float2*)part + ((size_t)s*4096 + row)*576;
#pragma unroll
    for (int r=0;r<9;r++){
      const float2 pv = pr[r*64+lane];
      v[r].x += pv.x; v[r].y += pv.y;
    }
  }
  float sm=0.f, ss=0.f;
#pragma unroll
  for (int r=0;r<9;r++){
    sm += v[r].x + v[r].y;
    ss += v[r].x*v[r].x + v[r].y*v[r].y;
  }
#pragma unroll
  for (int m=1;m<64;m<<=1){ sm += __shfl_xor(sm,m,64); ss += __shfl_xor(ss,m,64); }
  const float mean = sm*(1.0f/1152.0f);
  const float rs = rsqrtf(ss*(1.0f/1152.0f) - mean*mean + 1e-6f);
  const float2* gr2 = (const float2*)g;
  const float2* br2 = (const float2*)b;
#pragma unroll
  for (int r=0;r<9;r++){
    const int c = r*64+lane;
    if constexpr (WRITEX) ((float2*)xw)[(size_t)row*576 + c] = v[r];
    const float2 gg = gr2[c], bb = br2[c];
    const float o0 = (v[r].x-mean)*rs*gg.x + bb.x;
    const float o1 = (v[r].y-mean)*rs*gg.y + bb.y;
    if constexpr (OUTF32){
      ((float2*)out)[(size_t)row*576 + c] = make_float2(o0, o1);
    } else {
      __hip_bfloat162 hv;
      hv.x = __float2bfloat16(o0); hv.y = __float2bfloat16(o1);
      ((__hip_bfloat162*)out)[(size_t)row*576 + c] = hv;
    }
  }
}

// ---------------- im2col for 14x14 stride-14 conv: [4096, 608] bf16 ----
__global__ __launch_bounds__(256)
void im2col_kernel(const float* __restrict__ img, bf16* __restrict__ out)
{
  const int idx = blockIdx.x*256 + threadIdx.x;  // 4096*608
  const int kk = idx % 608;
  const int rr = idx / 608;
  float v = 0.f;
  if (kk < 588){
    const int bt = rr >> 10, n = rr & 1023;
    const int py = n >> 5, px = n & 31;
    const int ph = kk / 42;
    const int rem = kk - ph*42;
    const int pw = rem / 3;
    const int c  = rem - pw*3;
    v = img[(((size_t)bt*448 + py*14 + ph)*448 + px*14 + pw)*3 + c];
  }
  out[idx] = __float2bfloat16(v);
}

// ---------------- fp32 [K,N] -> bf16 [Np,Kp] transpose+convert, zero-pad -----------------
__global__ __launch_bounds__(256)
void transpose_cvt(const float* __restrict__ in, bf16* __restrict__ out,
                   int K, int N, int Kp, int Np)
{
  __shared__ float tile[32][33];
  const int nt = blockIdx.x*32, kt = blockIdx.y*32;
  const int r = threadIdx.x>>5, c = threadIdx.x&31;
#pragma unroll
  for (int i=0;i<4;i++){
    const int k = kt + r + i*8, n = nt + c;
    tile[r+i*8][c] = (k<K && n<N) ? in[(size_t)k*N + n] : 0.f;
  }
  __syncthreads();
#pragma unroll
  for (int i=0;i<4;i++){
    const int n = nt + r + i*8, k = kt + c;
    out[(size_t)n*Kp + k] = __float2bfloat16(tile[c][r+i*8]);
  }
}

// ---------------- bias packing + zero-buffer init ---------------
__global__ __launch_bounds__(256)
void pack_biases(const float* __restrict__ bq, const float* __restrict__ bk,
                 const float* __restrict__ bv, const float* __restrict__ b1,
                 int l, float* __restrict__ bqkv, float* __restrict__ b1p,
                 float4* __restrict__ zbuf)
{
  const int i = blockIdx.x*256 + threadIdx.x;
  if (i < 3456){
    float v;
    if (i < 1152)      v = bq[l*1152 + i];
    else if (i < 2304) v = bk[l*1152 + i - 1152];
    else               v = bv[l*1152 + i - 2304];
    bqkv[i] = v;
  }
  if (i < 4352) b1p[i] = (i < 4304) ? b1[l*4304 + i] : 0.f;
  if (i == 0) *zbuf = make_float4(0.f,0.f,0.f,0.f);
}

// -------- v repack transposed: qkv v-cols -> [64 bh][80 dh][1024 n] (pad rows 0) -----
__global__ __launch_bounds__(256)
void transpose_v(const bf16* __restrict__ src, bf16* __restrict__ dst)
{
  __shared__ bf16 tile[128][73];
  const int nc = blockIdx.x, bh = blockIdx.y;
  const int bt = bh>>4, hh = bh&15;
  const bf16* s = src + ((size_t)bt*1024 + nc*128)*3456 + 2304 + hh*72;
  for (int e=threadIdx.x; e<128*72; e+=256){
    const int n = e/72, dh = e - n*72;
    tile[n][dh] = s[(size_t)n*3456 + dh];
  }
  __syncthreads();
  bf16* d = dst + (size_t)bh*80*1024 + nc*128;
  const bf16 z = __float2bfloat16(0.f);
  for (int e=threadIdx.x; e<80*128; e+=256){
    const int dh = e>>7, n = e&127;
    d[(size_t)dh*1024 + n] = (dh<72) ? tile[n][dh] : z;
  }
}

// ---------------- flash attention, Q/K read directly from qkv [4096,3456] ------
// Q cols [hh*72, +72) pre-scaled by qs in QKV GEMM; K cols [1152+hh*72); V from vbuf.
__global__ __launch_bounds__(256,2)
void attn_kernel(const bf16* __restrict__ qkv, const bf16* __restrict__ vb,
                 const float4* __restrict__ zbuf, bf16* __restrict__ outp)
{
  __shared__ bf16 Ks[128*96];   // 24576 B  ([128 keys][96 dh], dh 72..95 zero)
  __shared__ bf16 Vs[80*128];   // 20480 B
  __shared__ bf16 Ps[64*136];   // 17408 B
  const int tid = threadIdx.x, wave = tid>>6, lane = tid&63;
  const int quad = lane>>4, l16 = lane&15;
  const int bh = blockIdx.y, q0 = blockIdx.x*64;
  const int bt = bh>>4, hh = bh&15;
  const bf16* vg = vb + (size_t)bh*80*1024;
  // Q fragments direct from qkv rows (144B per head slice, 16B aligned)
  bf16x8 af0{}, af1{}, af2{};
  {
    const bf16* qp = qkv + (size_t)(bt*1024 + q0 + wave*16 + l16)*3456 + hh*72 + quad*8;
    af0 = *(const bf16x8*)(qp);
    af1 = *(const bf16x8*)(qp+32);
    if (quad==0) af2 = *(const bf16x8*)(qp+64);
  }
  float mr[4], lr[4];
#pragma unroll
  for (int r=0;r<4;r++){ mr[r] = -3.0e38f; lr[r] = 0.f; }
  floatx4 oacc[5] = {};
  for (int kc=0;kc<8;kc++){
    __syncthreads();
    {
      // K chunk: rows kc*128..+127, 72 real dh -> [128][96] LDS, pad via zbuf
      const char* kcb = (const char*)(qkv + (size_t)(bt*1024 + kc*128)*3456 + 1152 + hh*72);
#pragma unroll
      for (int i=0;i<6;i++){
        const int u = (wave*6+i)*64 + lane;        // 0..1535 = row*12 + ch
        const int row = u/12, ch = u - row*12;
        const void* src = (ch<9) ? (const void*)(kcb + (size_t)row*6912 + ch*16)
                                 : (const void*)zbuf;
        gl_lds16(src, (char*)Ks + (wave*6+i)*1024);
      }
#pragma unroll
      for (int i=0;i<5;i++){
        const int sgi = wave*5+i;
        gl_lds16((const char*)vg + (size_t)(sgi*4 + (lane>>4))*2048 + kc*256 + (lane&15)*16,
                 (char*)Vs + sgi*1024);
      }
    }
    __syncthreads();
    floatx4 sc[8] = {};
#pragma unroll
    for (int ct=0;ct<8;ct++){
      const bf16* kr = Ks + (ct*16+l16)*96 + quad*8;
      sc[ct] = __builtin_amdgcn_mfma_f32_16x16x32_bf16(af0, *(const bf16x8*)(kr   ), sc[ct],0,0,0);
      sc[ct] = __builtin_amdgcn_mfma_f32_16x16x32_bf16(af1, *(const bf16x8*)(kr+32), sc[ct],0,0,0);
      sc[ct] = __builtin_amdgcn_mfma_f32_16x16x32_bf16(af2, *(const bf16x8*)(kr+64), sc[ct],0,0,0);
    }
    float cm[4];
#pragma unroll
    for (int r=0;r<4;r++){
      cm[r] = sc[0][r];
#pragma unroll
      for (int ct=1;ct<8;ct++) cm[r] = fmaxf(cm[r], sc[ct][r]);
    }
#pragma unroll
    for (int off=1; off<16; off<<=1)
#pragma unroll
      for (int r=0;r<4;r++) cm[r] = fmaxf(cm[r], __shfl_xor(cm[r], off, 64));
    float al[4], ls[4];
#pragma unroll
    for (int r=0;r<4;r++){
      const float mn = fmaxf(mr[r], cm[r]);
      al[r] = exp2f(mr[r]-mn);
      mr[r] = mn; ls[r] = 0.f;
    }
#pragma unroll
    for (int ct=0;ct<8;ct++){
#pragma unroll
      for (int r=0;r<4;r++){
        const float pv = exp2f(sc[ct][r]-mr[r]);
        ls[r] += pv;
        Ps[(wave*16+quad*4+r)*136 + ct*16+l16] = __float2bfloat16(pv);
      }
    }
#pragma unroll
    for (int off=1; off<16; off<<=1)
#pragma unroll
      for (int r=0;r<4;r++) ls[r] += __shfl_xor(ls[r], off, 64);
#pragma unroll
    for (int r=0;r<4;r++) lr[r] = lr[r]*al[r] + ls[r];
#pragma unroll
    for (int t=0;t<5;t++)
#pragma unroll
      for (int r=0;r<4;r++) oacc[t][r] *= al[r];
    __syncthreads();
#pragma unroll
    for (int ks=0;ks<4;ks++){
      const bf16x8 pf = *(const bf16x8*)(Ps + (wave*16+l16)*136 + ks*32 + quad*8);
#pragma unroll
      for (int t=0;t<5;t++){
        const bf16x8 vf = *(const bf16x8*)(Vs + (t*16+l16)*128 + ks*32 + quad*8);
        oacc[t] = __builtin_amdgcn_mfma_f32_16x16x32_bf16(pf, vf, oacc[t],0,0,0);
      }
    }
  }
#pragma unroll
  for (int t=0;t<5;t++){
    const int dh = t*16+l16;
    if (dh < 72){
#pragma unroll
      for (int r=0;r<4;r++){
        const int q = wave*16 + quad*4 + r;
        const float v = oacc[t][r] / lr[r];
        outp[((size_t)bt*1024 + q0 + q)*1152 + hh*72 + dh] = __float2bfloat16(v);
      }
    }
  }
}

extern "C" void kernel_launch(void* const* d_in, const int* in_sizes, int n_in,
                              void* d_out, int out_size, void* d_ws, size_t ws_size,
                              hipStream_t stream)
{
  (void)in_sizes; (void)n_in; (void)out_size; (void)ws_size;
  const float* images = (const float*)d_in[0];
  const float* conv_w = (const float*)d_in[1];
  const float* conv_b = (const float*)d_in[2];
  const float* pos_emb= (const float*)d_in[3];
  const float* ln1_g  = (const float*)d_in[4];
  const float* ln1_b  = (const float*)d_in[5];
  const float* Wq     = (const float*)d_in[6];
  const float* bq     = (const float*)d_in[7];
  const float* Wk     = (const float*)d_in[8];
  const float* bk     = (const float*)d_in[9];
  const float* Wv     = (const float*)d_in[10];
  const float* bv     = (const float*)d_in[11];
  const float* Wo     = (const float*)d_in[12];
  const float* bo     = (const float*)d_in[13];
  const float* ln2_g  = (const float*)d_in[14];
  const float* ln2_b  = (const float*)d_in[15];
  const float* W1     = (const float*)d_in[16];
  const float* b1     = (const float*)d_in[17];
  const float* W2     = (const float*)d_in[18];
  const float* b2     = (const float*)d_in[19];
  const float* lnf_g  = (const float*)d_in[20];
  const float* lnf_b  = (const float*)d_in[21];

  char* p = (char*)d_ws;
  auto take = [&](size_t nbytes)->char*{ char* q = p; p += (nbytes + 255) & ~(size_t)255; return q; };
  float* xw   = (float*)take(4096ull*1152*4);   // fp32 residual stream
  bf16* hbuf  = (bf16*) take(4096ull*1152*2);   // post-LN bf16
  bf16* h1    = (bf16*) take(4096ull*4352*2);   // MLP intermediate (padded)
  bf16* qkvr  = h1;                              // alias: qkv gemm out, dead before h1 written
  bf16* vbuf  = (bf16*) take(64ull*80*1024*2);
  bf16* imcol = vbuf;                            // alias: im2col dead before layer-0 transpose_v
  bf16* aout  = (bf16*) take(4096ull*1152*2);
  bf16* WqkvT = (bf16*) take(3456ull*1152*2);
  bf16* WoT   = (bf16*) take(1152ull*1152*2);
  bf16* W1T   = (bf16*) take(4352ull*1152*2);
  bf16* cwT   = W1T;                             // alias: conv wT dead before layer-0 W1T cvt
  bf16* W2T   = (bf16*) take(1152ull*4352*2);
  float* Ppart= (float*)take(4ull*4096*1152*4);  // split-K partials (max ks=4)
  float* bqkv = (float*)take(3456*4);
  float* b1p  = (float*)take(4352*4);
  float4* zbuf= (float4*)take(256);

  const float qscale = 1.4426950408889634f / sqrtf(72.0f);  // 1/sqrt(dh) with log2(e) folded

  // patch embedding: im2col GEMM, split-K ks=2 -> partials; reduce fused into ln1(l0)
  im2col_kernel<<<9728, 256, 0, stream>>>(images, imcol);
  transpose_cvt<<<dim3(36,19), 256, 0, stream>>>(conv_w, cwT, 588, 1152, 608, 1152);
  gemm_bf16<4><<<dim3(9,32,2), 256, 0, stream>>>(imcol, cwT, conv_b, Ppart, 1152, 608, 320, 0.f);

  for (int l=0;l<4;l++){
    transpose_cvt<<<dim3(36,36), 256, 0, stream>>>(Wq + (size_t)l*1152*1152, WqkvT,                1152,1152,1152,1152);
    transpose_cvt<<<dim3(36,36), 256, 0, stream>>>(Wk + (size_t)l*1152*1152, WqkvT + 1152ull*1152, 1152,1152,1152,1152);
    transpose_cvt<<<dim3(36,36), 256, 0, stream>>>(Wv + (size_t)l*1152*1152, WqkvT + 2304ull*1152, 1152,1152,1152,1152);
    transpose_cvt<<<dim3(36,36), 256, 0, stream>>>(Wo + (size_t)l*1152*1152, WoT, 1152,1152,1152,1152);
    transpose_cvt<<<dim3(136,36),256, 0, stream>>>(W1 + (size_t)l*1152*4304, W1T, 1152,4304,1152,4352);
    transpose_cvt<<<dim3(36,136),256, 0, stream>>>(W2 + (size_t)l*4304*1152, W2T, 4304,1152,4352,1152);
    pack_biases<<<17,256,0,stream>>>(bq,bk,bv,b1,l,bqkv,b1p,zbuf);

    // ln1: fused reduce of previous partials (patch ks=2 for l==0, MLP2 ks=4 otherwise)
    if (l==0)
      ln_red<0,1><<<1024,256,0,stream>>>(pos_emb, 1023u, Ppart, 2, ln1_g, ln1_b, xw, hbuf);
    else
      ln_red<0,1><<<1024,256,0,stream>>>(xw, 4095u, Ppart, 4, ln1_g + l*1152, ln1_b + l*1152, xw, hbuf);

    gemm_bf16<3><<<dim3(27,32,1),256,0,stream>>>(hbuf, WqkvT, bqkv, qkvr, 3456, 1152, 1152, qscale);
    transpose_v<<<dim3(8,64),256,0,stream>>>(qkvr, vbuf);
    attn_kernel<<<dim3(16,64),256,0,stream>>>(qkvr, vbuf, zbuf, aout);
    // O-proj: split-K ks=2 partials; reduce fused into ln2
    gemm_bf16<4><<<dim3(9,32,2),256,0,stream>>>(aout, WoT, bo + l*1152, Ppart, 1152, 1152, 576, 0.f);
    ln_red<0,1><<<1024,256,0,stream>>>(xw, 4095u, Ppart, 2, ln2_g + l*1152, ln2_b + l*1152, xw, hbuf);

    gemm_bf16<1><<<dim3(34,32,1),256,0,stream>>>(hbuf, W1T, b1p, h1, 4352, 1152, 1152, 0.f);
    // MLP2: split-K ks=4 partials; reduce fused into next ln1 (or final lnf)
    gemm_bf16<4><<<dim3(9,32,4),256,0,stream>>>(h1, W2T, b2 + l*1152, Ppart, 1152, 4352, 1088, 0.f);
  }
  ln_red<1,0><<<1024,256,0,stream>>>(xw, 4095u, Ppart, 4, lnf_g, lnf_b, nullptr, (float*)d_out);
}

// Round 3
// 1813.454 us; speedup vs baseline: 1.0817x; 1.0468x over previous
//
#include <hip/hip_runtime.h>
#include <hip/hip_bf16.h>
#include <stdint.h>
#include <math.h>

typedef __hip_bfloat16 bf16;
typedef __attribute__((ext_vector_type(4))) float floatx4;
typedef __attribute__((ext_vector_type(8))) __bf16 bf16x8;

typedef __attribute__((address_space(1))) void gvoid_t;
typedef __attribute__((address_space(3))) void lvoid_t;

__device__ __forceinline__ void gl_lds16(const void* g, void* l){
  __builtin_amdgcn_global_load_lds((gvoid_t*)g, (lvoid_t*)l, 16, 0, 0);
}

__device__ __forceinline__ float gelu_f(float v){
  float u = 0.7978845608028654f*(v + 0.044715f*v*v*v);
  float e = __expf(2.0f*u);
  return v*(1.0f - 1.0f/(e+1.0f));
}

// ---------------- GEMM: C[M,N] = A[M,K](bf16) @ BT[N,K](bf16) + bias ----------
// LDS tiles use low-2-bit XOR chunk swizzle (c' = c ^ (row&3)) -> conflict-free b128 reads.
// MODE 0: bf16 C = acc+bias
// MODE 1: bf16 C = gelu(acc+bias)
// MODE 3: bf16 C = (acc+bias) * (n0<1152 ? qs : 1)   [QKV with folded q-scale]
// MODE 4: f32 partial C[s][M][N] = acc + (s==0 ? bias : 0)   [split-K, blockIdx.z = s]
template<int MODE>
__global__ __launch_bounds__(256,2)
void gemm_bf16(const bf16* __restrict__ A, const bf16* __restrict__ BT,
               const float* __restrict__ bias, void* __restrict__ C,
               int N, int K, int kc, float qs)
{
  __shared__ bf16 As[128*32];
  __shared__ bf16 Bs[128*32];
  const int tid  = threadIdx.x;
  const int wave = tid>>6, lane = tid&63;
  const int quad = lane>>4, l16 = lane&15;
  const int m0 = blockIdx.y*128, n0 = blockIdx.x*128;
  const int s  = blockIdx.z;
  const int kb = s*kc;
  const int ke = min(K, kb + kc);
  const int wm = (wave&1)*64, wn = (wave>>1)*64;
  floatx4 acc[4][4] = {};
  // staging with swizzled source chunk: row = wave*32 + seg*16 + (lane>>2), chunk = (lane&3)^(row&3)
  const int schunk = (lane&3) ^ ((lane>>2)&3);
  const bf16* ag = A  + (size_t)(m0 + wave*32 + (lane>>2))*K + schunk*8;
  const bf16* bg = BT + (size_t)(n0 + wave*32 + (lane>>2))*K + schunk*8;
  bf16* asl = As + wave*1024;
  bf16* bsl = Bs + wave*1024;
  const size_t row16 = (size_t)16*K;
  const int rsw = (l16&3);   // read-side swizzle key (row&3 == l16&3 for all read rows)
  for (int k0=kb; k0<ke; k0+=32){
    __syncthreads();
    gl_lds16(ag + k0,          asl);
    gl_lds16(ag + k0 + row16,  asl + 512);
    gl_lds16(bg + k0,          bsl);
    gl_lds16(bg + k0 + row16,  bsl + 512);
    __syncthreads();
    bf16x8 af[4], bfr[4];
#pragma unroll
    for (int i=0;i<4;i++) af[i]  = *(const bf16x8*)(As + (wm + i*16 + l16)*32 + (quad^rsw)*8);
#pragma unroll
    for (int j=0;j<4;j++) bfr[j] = *(const bf16x8*)(Bs + (wn + j*16 + l16)*32 + (quad^rsw)*8);
#pragma unroll
    for (int i=0;i<4;i++)
#pragma unroll
      for (int j=0;j<4;j++)
        acc[i][j] = __builtin_amdgcn_mfma_f32_16x16x32_bf16(af[i], bfr[j], acc[i][j], 0,0,0);
  }
  const float scale = (MODE==3 && n0<1152) ? qs : 1.0f;
#pragma unroll
  for (int i=0;i<4;i++){
    const int gr0 = m0 + wm + i*16 + quad*4;
#pragma unroll
    for (int j=0;j<4;j++){
      const int gc = n0 + wn + j*16 + l16;
      const float bv = (MODE!=4 || s==0) ? bias[gc] : 0.f;
#pragma unroll
      for (int r=0;r<4;r++){
        const int gr = gr0 + r;
        float v = acc[i][j][r] + bv;
        if constexpr (MODE==1) v = gelu_f(v);
        if constexpr (MODE==3) v *= scale;
        if constexpr (MODE==4){
          ((float*)C)[((size_t)s*4096 + gr)*N + gc] = v;
        } else {
          ((bf16*)C)[(size_t)gr*N + gc] = __float2bfloat16(v);
        }
      }
    }
  }
}

// ---------------- fused split-K reduce + residual + LayerNorm ----------------
template<int OUTF32, int WRITEX>
__global__ __launch_bounds__(256)
void ln_red(const float* __restrict__ base, unsigned bmask,
            const float* __restrict__ part, int ks,
            const float* __restrict__ g, const float* __restrict__ b,
            float* __restrict__ xw, void* __restrict__ out)
{
  const int row  = blockIdx.x*4 + (threadIdx.x>>6);
  const int lane = threadIdx.x & 63;
  const float2* br = (const float2*)base + (size_t)(row & bmask)*576;
  float2 v[9];
#pragma unroll
  for (int r=0;r<9;r++) v[r] = br[r*64+lane];
  for (int s=0;s<ks;s++){
    const float2* pr = (const float2*)part + ((size_t)s*4096 + row)*576;
#pragma unroll
    for (int r=0;r<9;r++){
      const float2 pv = pr[r*64+lane];
      v[r].x += pv.x; v[r].y += pv.y;
    }
  }
  float sm=0.f, ss=0.f;
#pragma unroll
  for (int r=0;r<9;r++){
    sm += v[r].x + v[r].y;
    ss += v[r].x*v[r].x + v[r].y*v[r].y;
  }
#pragma unroll
  for (int m=1;m<64;m<<=1){ sm += __shfl_xor(sm,m,64); ss += __shfl_xor(ss,m,64); }
  const float mean = sm*(1.0f/1152.0f);
  const float rs = rsqrtf(ss*(1.0f/1152.0f) - mean*mean + 1e-6f);
  const float2* gr2 = (const float2*)g;
  const float2* br2 = (const float2*)b;
#pragma unroll
  for (int r=0;r<9;r++){
    const int c = r*64+lane;
    if constexpr (WRITEX) ((float2*)xw)[(size_t)row*576 + c] = v[r];
    const float2 gg = gr2[c], bb = br2[c];
    const float o0 = (v[r].x-mean)*rs*gg.x + bb.x;
    const float o1 = (v[r].y-mean)*rs*gg.y + bb.y;
    if constexpr (OUTF32){
      ((float2*)out)[(size_t)row*576 + c] = make_float2(o0, o1);
    } else {
      __hip_bfloat162 hv;
      hv.x = __float2bfloat16(o0); hv.y = __float2bfloat16(o1);
      ((__hip_bfloat162*)out)[(size_t)row*576 + c] = hv;
    }
  }
}

// ---------------- im2col for 14x14 stride-14 conv: [4096, 608] bf16 ----
__global__ __launch_bounds__(256)
void im2col_kernel(const float* __restrict__ img, bf16* __restrict__ out)
{
  const int idx = blockIdx.x*256 + threadIdx.x;  // 4096*608
  const int kk = idx % 608;
  const int rr = idx / 608;
  float v = 0.f;
  if (kk < 588){
    const int bt = rr >> 10, n = rr & 1023;
    const int py = n >> 5, px = n & 31;
    const int ph = kk / 42;
    const int rem = kk - ph*42;
    const int pw = rem / 3;
    const int c  = rem - pw*3;
    v = img[(((size_t)bt*448 + py*14 + ph)*448 + px*14 + pw)*3 + c];
  }
  out[idx] = __float2bfloat16(v);
}

// ---------------- fp32 [K,N] -> bf16 [Np,Kp] transpose+convert, zero-pad -----------------
__global__ __launch_bounds__(256)
void transpose_cvt(const float* __restrict__ in, bf16* __restrict__ out,
                   int K, int N, int Kp, int Np)
{
  __shared__ float tile[32][33];
  const int nt = blockIdx.x*32, kt = blockIdx.y*32;
  const int r = threadIdx.x>>5, c = threadIdx.x&31;
#pragma unroll
  for (int i=0;i<4;i++){
    const int k = kt + r + i*8, n = nt + c;
    tile[r+i*8][c] = (k<K && n<N) ? in[(size_t)k*N + n] : 0.f;
  }
  __syncthreads();
#pragma unroll
  for (int i=0;i<4;i++){
    const int n = nt + r + i*8, k = kt + c;
    out[(size_t)n*Kp + k] = __float2bfloat16(tile[c][r+i*8]);
  }
}

// ---------------- bias packing + zero-buffer init ---------------
__global__ __launch_bounds__(256)
void pack_biases(const float* __restrict__ bq, const float* __restrict__ bk,
                 const float* __restrict__ bv, const float* __restrict__ b1,
                 int l, float* __restrict__ bqkv, float* __restrict__ b1p,
                 float4* __restrict__ zbuf)
{
  const int i = blockIdx.x*256 + threadIdx.x;
  if (i < 3456){
    float v;
    if (i < 1152)      v = bq[l*1152 + i];
    else if (i < 2304) v = bk[l*1152 + i - 1152];
    else               v = bv[l*1152 + i - 2304];
    bqkv[i] = v;
  }
  if (i < 4352) b1p[i] = (i < 4304) ? b1[l*4304 + i] : 0.f;
  if (i == 0) *zbuf = make_float4(0.f,0.f,0.f,0.f);
}

// -------- v repack transposed: qkv v-cols -> [64 bh][80 dh][1024 n] (pad rows 0) -----
__global__ __launch_bounds__(256)
void transpose_v(const bf16* __restrict__ src, bf16* __restrict__ dst)
{
  __shared__ bf16 tile[128][73];
  const int nc = blockIdx.x, bh = blockIdx.y;
  const int bt = bh>>4, hh = bh&15;
  const bf16* s = src + ((size_t)bt*1024 + nc*128)*3456 + 2304 + hh*72;
  for (int e=threadIdx.x; e<128*72; e+=256){
    const int n = e/72, dh = e - n*72;
    tile[n][dh] = s[(size_t)n*3456 + dh];
  }
  __syncthreads();
  bf16* d = dst + (size_t)bh*80*1024 + nc*128;
  const bf16 z = __float2bfloat16(0.f);
  for (int e=threadIdx.x; e<80*128; e+=256){
    const int dh = e>>7, n = e&127;
    d[(size_t)dh*1024 + n] = (dh<72) ? tile[n][dh] : z;
  }
}

// ---------------- flash attention, swizzled LDS ------
// Ks: [128 keys][96 dh], 12 chunks/row, low-2 swizzle within 4-chunk groups.
// Vs: [80 dh][128 keys], 16 chunks/row, low-3 swizzle.
// Ps: [64 q][128 keys],  16 chunks/row, low-3 swizzle.
__global__ __launch_bounds__(256,2)
void attn_kernel(const bf16* __restrict__ qkv, const bf16* __restrict__ vb,
                 const float4* __restrict__ zbuf, bf16* __restrict__ outp)
{
  __shared__ bf16 Ks[128*96];   // 24576 B
  __shared__ bf16 Vs[80*128];   // 20480 B
  __shared__ bf16 Ps[64*128];   // 16384 B
  const int tid = threadIdx.x, wave = tid>>6, lane = tid&63;
  const int quad = lane>>4, l16 = lane&15;
  const int bh = blockIdx.y, q0 = blockIdx.x*64;
  const int bt = bh>>4, hh = bh&15;
  const bf16* vg = vb + (size_t)bh*80*1024;
  bf16x8 af0{}, af1{}, af2{};
  {
    const bf16* qp = qkv + (size_t)(bt*1024 + q0 + wave*16 + l16)*3456 + hh*72 + quad*8;
    af0 = *(const bf16x8*)(qp);
    af1 = *(const bf16x8*)(qp+32);
    if (quad==0) af2 = *(const bf16x8*)(qp+64);
  }
  float mr[4], lr[4];
#pragma unroll
  for (int r=0;r<4;r++){ mr[r] = -3.0e38f; lr[r] = 0.f; }
  floatx4 oacc[5] = {};
  for (int kc=0;kc<8;kc++){
    __syncthreads();
    {
      // K chunk staging: LDS chunk position u holds data chunk c = (p&12)|((p&3)^(row&3))
      const char* kcb = (const char*)(qkv + (size_t)(bt*1024 + kc*128)*3456 + 1152 + hh*72);
#pragma unroll
      for (int i=0;i<6;i++){
        const int u = (wave*6+i)*64 + lane;      // 0..1535
        const int row = u/12;
        const int pp = u - row*12;
        const int c = (pp & 12) | ((pp & 3) ^ (row & 3));
        const void* src = (c<9) ? (const void*)(kcb + (size_t)row*6912 + c*16)
                                : (const void*)zbuf;
        gl_lds16(src, (char*)Ks + (size_t)(wave*6+i)*1024);
      }
      // V chunk staging: position p in row holds data chunk c = (p&8)|((p&7)^(row&7))
#pragma unroll
      for (int i=0;i<5;i++){
        const int u = (wave*5+i)*64 + lane;      // 0..1279
        const int row = u>>4;
        const int pp = u & 15;
        const int c = (pp & 8) | ((pp & 7) ^ (row & 7));
        gl_lds16((const char*)vg + (size_t)row*2048 + kc*256 + c*16,
                 (char*)Vs + (size_t)(wave*5+i)*1024);
      }
    }
    __syncthreads();
    // S = Q K^T; K row = ct*16+l16 (row&3 == l16&3), data chunk {quad,4+quad,8+quad} -> swizzled
    floatx4 sc[8] = {};
    const int ksw = (quad ^ (l16&3))*8;
#pragma unroll
    for (int ct=0;ct<8;ct++){
      const bf16* kr = Ks + (ct*16+l16)*96 + ksw;
      sc[ct] = __builtin_amdgcn_mfma_f32_16x16x32_bf16(af0, *(const bf16x8*)(kr   ), sc[ct],0,0,0);
      sc[ct] = __builtin_amdgcn_mfma_f32_16x16x32_bf16(af1, *(const bf16x8*)(kr+32), sc[ct],0,0,0);
      sc[ct] = __builtin_amdgcn_mfma_f32_16x16x32_bf16(af2, *(const bf16x8*)(kr+64), sc[ct],0,0,0);
    }
    float cm[4];
#pragma unroll
    for (int r=0;r<4;r++){
      cm[r] = sc[0][r];
#pragma unroll
      for (int ct=1;ct<8;ct++) cm[r] = fmaxf(cm[r], sc[ct][r]);
    }
#pragma unroll
    for (int off=1; off<16; off<<=1)
#pragma unroll
      for (int r=0;r<4;r++) cm[r] = fmaxf(cm[r], __shfl_xor(cm[r], off, 64));
    float al[4], ls[4];
#pragma unroll
    for (int r=0;r<4;r++){
      const float mn = fmaxf(mr[r], cm[r]);
      al[r] = exp2f(mr[r]-mn);
      mr[r] = mn; ls[r] = 0.f;
    }
    // P store: row = wave*16+quad*4+r, col = ct*16+l16; swizzled chunk position
#pragma unroll
    for (int ct=0;ct<8;ct++){
#pragma unroll
      for (int r=0;r<4;r++){
        const float pv = exp2f(sc[ct][r]-mr[r]);
        ls[r] += pv;
        const int row = wave*16+quad*4+r;
        const int c = ct*2 + (l16>>3);
        const int pp = (c & 8) | ((c & 7) ^ (row & 7));
        Ps[row*128 + pp*8 + (l16&7)] = __float2bfloat16(pv);
      }
    }
#pragma unroll
    for (int off=1; off<16; off<<=1)
#pragma unroll
      for (int r=0;r<4;r++) ls[r] += __shfl_xor(ls[r], off, 64);
#pragma unroll
    for (int r=0;r<4;r++) lr[r] = lr[r]*al[r] + ls[r];
#pragma unroll
    for (int t=0;t<5;t++)
#pragma unroll
      for (int r=0;r<4;r++) oacc[t][r] *= al[r];
    __syncthreads();
    // O += P @ V  (Ps row = wave*16+l16, Vs row = t*16+l16; both row&7 == l16&7)
#pragma unroll
    for (int ks=0;ks<4;ks++){
#pragma unroll
      for (int q2=0;q2<1;q2++){}  // (keep structure flat)
      const int c = ks*4 + quad;
      const int pp = (c & 8) | ((c & 7) ^ (l16 & 7));
      const bf16x8 pf = *(const bf16x8*)(Ps + (wave*16+l16)*128 + pp*8);
#pragma unroll
      for (int t=0;t<5;t++){
        const bf16x8 vf = *(const bf16x8*)(Vs + (t*16+l16)*128 + pp*8);
        oacc[t] = __builtin_amdgcn_mfma_f32_16x16x32_bf16(pf, vf, oacc[t],0,0,0);
      }
    }
  }
#pragma unroll
  for (int t=0;t<5;t++){
    const int dh = t*16+l16;
    if (dh < 72){
#pragma unroll
      for (int r=0;r<4;r++){
        const int q = wave*16 + quad*4 + r;
        const float v = oacc[t][r] / lr[r];
        outp[((size_t)bt*1024 + q0 + q)*1152 + hh*72 + dh] = __float2bfloat16(v);
      }
    }
  }
}

extern "C" void kernel_launch(void* const* d_in, const int* in_sizes, int n_in,
                              void* d_out, int out_size, void* d_ws, size_t ws_size,
                              hipStream_t stream)
{
  (void)in_sizes; (void)n_in; (void)out_size; (void)ws_size;
  const float* images = (const float*)d_in[0];
  const float* conv_w = (const float*)d_in[1];
  const float* conv_b = (const float*)d_in[2];
  const float* pos_emb= (const float*)d_in[3];
  const float* ln1_g  = (const float*)d_in[4];
  const float* ln1_b  = (const float*)d_in[5];
  const float* Wq     = (const float*)d_in[6];
  const float* bq     = (const float*)d_in[7];
  const float* Wk     = (const float*)d_in[8];
  const float* bk     = (const float*)d_in[9];
  const float* Wv     = (const float*)d_in[10];
  const float* bv     = (const float*)d_in[11];
  const float* Wo     = (const float*)d_in[12];
  const float* bo     = (const float*)d_in[13];
  const float* ln2_g  = (const float*)d_in[14];
  const float* ln2_b  = (const float*)d_in[15];
  const float* W1     = (const float*)d_in[16];
  const float* b1     = (const float*)d_in[17];
  const float* W2     = (const float*)d_in[18];
  const float* b2     = (const float*)d_in[19];
  const float* lnf_g  = (const float*)d_in[20];
  const float* lnf_b  = (const float*)d_in[21];

  char* p = (char*)d_ws;
  auto take = [&](size_t nbytes)->char*{ char* q = p; p += (nbytes + 255) & ~(size_t)255; return q; };
  float* xw   = (float*)take(4096ull*1152*4);
  bf16* hbuf  = (bf16*) take(4096ull*1152*2);
  bf16* h1    = (bf16*) take(4096ull*4352*2);
  bf16* qkvr  = h1;
  bf16* vbuf  = (bf16*) take(64ull*80*1024*2);
  bf16* imcol = vbuf;
  bf16* aout  = (bf16*) take(4096ull*1152*2);
  bf16* WqkvT = (bf16*) take(3456ull*1152*2);
  bf16* WoT   = (bf16*) take(1152ull*1152*2);
  bf16* W1T   = (bf16*) take(4352ull*1152*2);
  bf16* cwT   = W1T;
  bf16* W2T   = (bf16*) take(1152ull*4352*2);
  float* Ppart= (float*)take(4ull*4096*1152*4);
  float* bqkv = (float*)take(3456*4);
  float* b1p  = (float*)take(4352*4);
  float4* zbuf= (float4*)take(256);

  const float qscale = 1.4426950408889634f / sqrtf(72.0f);

  im2col_kernel<<<9728, 256, 0, stream>>>(images, imcol);
  transpose_cvt<<<dim3(36,19), 256, 0, stream>>>(conv_w, cwT, 588, 1152, 608, 1152);
  gemm_bf16<4><<<dim3(9,32,2), 256, 0, stream>>>(imcol, cwT, conv_b, Ppart, 1152, 608, 320, 0.f);

  for (int l=0;l<4;l++){
    transpose_cvt<<<dim3(36,36), 256, 0, stream>>>(Wq + (size_t)l*1152*1152, WqkvT,                1152,1152,1152,1152);
    transpose_cvt<<<dim3(36,36), 256, 0, stream>>>(Wk + (size_t)l*1152*1152, WqkvT + 1152ull*1152, 1152,1152,1152,1152);
    transpose_cvt<<<dim3(36,36), 256, 0, stream>>>(Wv + (size_t)l*1152*1152, WqkvT + 2304ull*1152, 1152,1152,1152,1152);
    transpose_cvt<<<dim3(36,36), 256, 0, stream>>>(Wo + (size_t)l*1152*1152, WoT, 1152,1152,1152,1152);
    transpose_cvt<<<dim3(136,36),256, 0, stream>>>(W1 + (size_t)l*1152*4304, W1T, 1152,4304,1152,4352);
    transpose_cvt<<<dim3(36,136),256, 0, stream>>>(W2 + (size_t)l*4304*1152, W2T, 4304,1152,4352,1152);
    pack_biases<<<17,256,0,stream>>>(bq,bk,bv,b1,l,bqkv,b1p,zbuf);

    if (l==0)
      ln_red<0,1><<<1024,256,0,stream>>>(pos_emb, 1023u, Ppart, 2, ln1_g, ln1_b, xw, hbuf);
    else
      ln_red<0,1><<<1024,256,0,stream>>>(xw, 4095u, Ppart, 4, ln1_g + l*1152, ln1_b + l*1152, xw, hbuf);

    gemm_bf16<3><<<dim3(27,32,1),256,0,stream>>>(hbuf, WqkvT, bqkv, qkvr, 3456, 1152, 1152, qscale);
    transpose_v<<<dim3(8,64),256,0,stream>>>(qkvr, vbuf);
    attn_kernel<<<dim3(16,64),256,0,stream>>>(qkvr, vbuf, zbuf, aout);
    gemm_bf16<4><<<dim3(9,32,2),256,0,stream>>>(aout, WoT, bo + l*1152, Ppart, 1152, 1152, 576, 0.f);
    ln_red<0,1><<<1024,256,0,stream>>>(xw, 4095u, Ppart, 2, ln2_g + l*1152, ln2_b + l*1152, xw, hbuf);

    gemm_bf16<1><<<dim3(34,32,1),256,0,stream>>>(hbuf, W1T, b1p, h1, 4352, 1152, 1152, 0.f);
    gemm_bf16<4><<<dim3(9,32,4),256,0,stream>>>(h1, W2T, b2 + l*1152, Ppart, 1152, 4352, 1088, 0.f);
  }
  ln_red<1,0><<<1024,256,0,stream>>>(xw, 4095u, Ppart, 4, lnf_g, lnf_b, nullptr, (float*)d_out);
}

// Round 4
// 1769.883 us; speedup vs baseline: 1.1084x; 1.0246x over previous
//
#include <hip/hip_runtime.h>
#include <hip/hip_bf16.h>
#include <stdint.h>
#include <math.h>

typedef __hip_bfloat16 bf16;
typedef __attribute__((ext_vector_type(4))) float floatx4;
typedef __attribute__((ext_vector_type(8))) __bf16 bf16x8;

typedef __attribute__((address_space(1))) void gvoid_t;
typedef __attribute__((address_space(3))) void lvoid_t;

__device__ __forceinline__ void gl_lds16(const void* g, void* l){
  __builtin_amdgcn_global_load_lds((gvoid_t*)g, (lvoid_t*)l, 16, 0, 0);
}

__device__ __forceinline__ float gelu_f(float v){
  float u = 0.7978845608028654f*(v + 0.044715f*v*v*v);
  float e = __expf(2.0f*u);
  return v*(1.0f - 1.0f/(e+1.0f));
}

// ---------------- GEMM: C[M,N] = A[M,K](bf16) @ BT[N,K](bf16) + bias ----------
// MODE 0: bf16 C = acc+bias
// MODE 1: bf16 C = gelu(acc+bias)
// MODE 3: bf16 C = (acc+bias) * (n0<1152 ? qs : 1)   [QKV with folded q-scale]
// MODE 4: bf16 partial C[s][M][N] = acc + (s==0 ? bias : 0)   [split-K, blockIdx.z = s]
// launch_bounds(256,4): VGPR~56 + 64 acc fits 128-unified -> 4 blocks/CU (occupancy was the limiter)
template<int MODE>
__global__ __launch_bounds__(256,4)
void gemm_bf16(const bf16* __restrict__ A, const bf16* __restrict__ BT,
               const float* __restrict__ bias, void* __restrict__ C,
               int N, int K, int kc, float qs)
{
  __shared__ bf16 As[128*32];
  __shared__ bf16 Bs[128*32];
  const int tid  = threadIdx.x;
  const int wave = tid>>6, lane = tid&63;
  const int quad = lane>>4, l16 = lane&15;
  const int m0 = blockIdx.y*128, n0 = blockIdx.x*128;
  const int s  = blockIdx.z;
  const int kb = s*kc;
  const int ke = min(K, kb + kc);
  const int wm = (wave&1)*64, wn = (wave>>1)*64;
  floatx4 acc[4][4] = {};
  const bf16* ag = A  + (size_t)(m0 + wave*32 + (lane>>2))*K + (lane&3)*8;
  const bf16* bg = BT + (size_t)(n0 + wave*32 + (lane>>2))*K + (lane&3)*8;
  bf16* asl = As + wave*1024;
  bf16* bsl = Bs + wave*1024;
  const size_t row16 = (size_t)16*K;
  for (int k0=kb; k0<ke; k0+=32){
    __syncthreads();
    gl_lds16(ag + k0,          asl);
    gl_lds16(ag + k0 + row16,  asl + 512);
    gl_lds16(bg + k0,          bsl);
    gl_lds16(bg + k0 + row16,  bsl + 512);
    __syncthreads();
    bf16x8 af[4], bfr[4];
#pragma unroll
    for (int i=0;i<4;i++) af[i]  = *(const bf16x8*)(As + (wm + i*16 + l16)*32 + quad*8);
#pragma unroll
    for (int j=0;j<4;j++) bfr[j] = *(const bf16x8*)(Bs + (wn + j*16 + l16)*32 + quad*8);
#pragma unroll
    for (int i=0;i<4;i++)
#pragma unroll
      for (int j=0;j<4;j++)
        acc[i][j] = __builtin_amdgcn_mfma_f32_16x16x32_bf16(af[i], bfr[j], acc[i][j], 0,0,0);
  }
  const float scale = (MODE==3 && n0<1152) ? qs : 1.0f;
#pragma unroll
  for (int i=0;i<4;i++){
    const int gr0 = m0 + wm + i*16 + quad*4;
#pragma unroll
    for (int j=0;j<4;j++){
      const int gc = n0 + wn + j*16 + l16;
      const float bv = (MODE!=4 || s==0) ? bias[gc] : 0.f;
#pragma unroll
      for (int r=0;r<4;r++){
        const int gr = gr0 + r;
        float v = acc[i][j][r] + bv;
        if constexpr (MODE==1) v = gelu_f(v);
        if constexpr (MODE==3) v *= scale;
        if constexpr (MODE==4){
          ((bf16*)C)[((size_t)s*4096 + gr)*N + gc] = __float2bfloat16(v);
        } else {
          ((bf16*)C)[(size_t)gr*N + gc] = __float2bfloat16(v);
        }
      }
    }
  }
}

// ---------------- fused split-K reduce + residual + LayerNorm ----------------
// x = base[(row&bmask)] + sum_s part_bf16[s][row]; optional xw write; out = LN(x)*g+b
template<int OUTF32, int WRITEX>
__global__ __launch_bounds__(256)
void ln_red(const float* __restrict__ base, unsigned bmask,
            const bf16* __restrict__ part, int ks,
            const float* __restrict__ g, const float* __restrict__ b,
            float* __restrict__ xw, void* __restrict__ out)
{
  const int row  = blockIdx.x*4 + (threadIdx.x>>6);
  const int lane = threadIdx.x & 63;
  const float2* br = (const float2*)base + (size_t)(row & bmask)*576;
  float2 v[9];
#pragma unroll
  for (int r=0;r<9;r++) v[r] = br[r*64+lane];
  for (int s=0;s<ks;s++){
    const __hip_bfloat162* pr = (const __hip_bfloat162*)part + ((size_t)s*4096 + row)*576;
#pragma unroll
    for (int r=0;r<9;r++){
      const float2 pv = __bfloat1622float2(pr[r*64+lane]);
      v[r].x += pv.x; v[r].y += pv.y;
    }
  }
  float sm=0.f, ss=0.f;
#pragma unroll
  for (int r=0;r<9;r++){
    sm += v[r].x + v[r].y;
    ss += v[r].x*v[r].x + v[r].y*v[r].y;
  }
#pragma unroll
  for (int m=1;m<64;m<<=1){ sm += __shfl_xor(sm,m,64); ss += __shfl_xor(ss,m,64); }
  const float mean = sm*(1.0f/1152.0f);
  const float rs = rsqrtf(ss*(1.0f/1152.0f) - mean*mean + 1e-6f);
  const float2* gr2 = (const float2*)g;
  const float2* br2 = (const float2*)b;
#pragma unroll
  for (int r=0;r<9;r++){
    const int c = r*64+lane;
    if constexpr (WRITEX) ((float2*)xw)[(size_t)row*576 + c] = v[r];
    const float2 gg = gr2[c], bb = br2[c];
    const float o0 = (v[r].x-mean)*rs*gg.x + bb.x;
    const float o1 = (v[r].y-mean)*rs*gg.y + bb.y;
    if constexpr (OUTF32){
      ((float2*)out)[(size_t)row*576 + c] = make_float2(o0, o1);
    } else {
      __hip_bfloat162 hv;
      hv.x = __float2bfloat16(o0); hv.y = __float2bfloat16(o1);
      ((__hip_bfloat162*)out)[(size_t)row*576 + c] = hv;
    }
  }
}

// ---------------- im2col for 14x14 stride-14 conv: [4096, 608] bf16 ----
__global__ __launch_bounds__(256)
void im2col_kernel(const float* __restrict__ img, bf16* __restrict__ out)
{
  const int idx = blockIdx.x*256 + threadIdx.x;  // 4096*608
  const int kk = idx % 608;
  const int rr = idx / 608;
  float v = 0.f;
  if (kk < 588){
    const int bt = rr >> 10, n = rr & 1023;
    const int py = n >> 5, px = n & 31;
    const int ph = kk / 42;
    const int rem = kk - ph*42;
    const int pw = rem / 3;
    const int c  = rem - pw*3;
    v = img[(((size_t)bt*448 + py*14 + ph)*448 + px*14 + pw)*3 + c];
  }
  out[idx] = __float2bfloat16(v);
}

// ---------------- fp32 [K,N] -> bf16 [Np,Kp] transpose+convert, zero-pad -----------------
__global__ __launch_bounds__(256)
void transpose_cvt(const float* __restrict__ in, bf16* __restrict__ out,
                   int K, int N, int Kp, int Np)
{
  __shared__ float tile[32][33];
  const int nt = blockIdx.x*32, kt = blockIdx.y*32;
  const int r = threadIdx.x>>5, c = threadIdx.x&31;
#pragma unroll
  for (int i=0;i<4;i++){
    const int k = kt + r + i*8, n = nt + c;
    tile[r+i*8][c] = (k<K && n<N) ? in[(size_t)k*N + n] : 0.f;
  }
  __syncthreads();
#pragma unroll
  for (int i=0;i<4;i++){
    const int n = nt + r + i*8, k = kt + c;
    out[(size_t)n*Kp + k] = __float2bfloat16(tile[c][r+i*8]);
  }
}

// ---------------- bias packing + zero-buffer init ---------------
__global__ __launch_bounds__(256)
void pack_biases(const float* __restrict__ bq, const float* __restrict__ bk,
                 const float* __restrict__ bv, const float* __restrict__ b1,
                 int l, float* __restrict__ bqkv, float* __restrict__ b1p,
                 float4* __restrict__ zbuf)
{
  const int i = blockIdx.x*256 + threadIdx.x;
  if (i < 3456){
    float v;
    if (i < 1152)      v = bq[l*1152 + i];
    else if (i < 2304) v = bk[l*1152 + i - 1152];
    else               v = bv[l*1152 + i - 2304];
    bqkv[i] = v;
  }
  if (i < 4352) b1p[i] = (i < 4304) ? b1[l*4304 + i] : 0.f;
  if (i == 0) *zbuf = make_float4(0.f,0.f,0.f,0.f);
}

// -------- v repack transposed: qkv v-cols -> [64 bh][80 dh][1024 n] (pad rows 0) -----
__global__ __launch_bounds__(256)
void transpose_v(const bf16* __restrict__ src, bf16* __restrict__ dst)
{
  __shared__ bf16 tile[128][73];
  const int nc = blockIdx.x, bh = blockIdx.y;
  const int bt = bh>>4, hh = bh&15;
  const bf16* s = src + ((size_t)bt*1024 + nc*128)*3456 + 2304 + hh*72;
  for (int e=threadIdx.x; e<128*72; e+=256){
    const int n = e/72, dh = e - n*72;
    tile[n][dh] = s[(size_t)n*3456 + dh];
  }
  __syncthreads();
  bf16* d = dst + (size_t)bh*80*1024 + nc*128;
  const bf16 z = __float2bfloat16(0.f);
  for (int e=threadIdx.x; e<80*128; e+=256){
    const int dh = e>>7, n = e&127;
    d[(size_t)dh*1024 + n] = (dh<72) ? tile[n][dh] : z;
  }
}

// ---------------- flash attention, swizzled LDS ------
__global__ __launch_bounds__(256,2)
void attn_kernel(const bf16* __restrict__ qkv, const bf16* __restrict__ vb,
                 const float4* __restrict__ zbuf, bf16* __restrict__ outp)
{
  __shared__ bf16 Ks[128*96];   // 24576 B
  __shared__ bf16 Vs[80*128];   // 20480 B
  __shared__ bf16 Ps[64*128];   // 16384 B
  const int tid = threadIdx.x, wave = tid>>6, lane = tid&63;
  const int quad = lane>>4, l16 = lane&15;
  const int bh = blockIdx.y, q0 = blockIdx.x*64;
  const int bt = bh>>4, hh = bh&15;
  const bf16* vg = vb + (size_t)bh*80*1024;
  bf16x8 af0{}, af1{}, af2{};
  {
    const bf16* qp = qkv + (size_t)(bt*1024 + q0 + wave*16 + l16)*3456 + hh*72 + quad*8;
    af0 = *(const bf16x8*)(qp);
    af1 = *(const bf16x8*)(qp+32);
    if (quad==0) af2 = *(const bf16x8*)(qp+64);
  }
  float mr[4], lr[4];
#pragma unroll
  for (int r=0;r<4;r++){ mr[r] = -3.0e38f; lr[r] = 0.f; }
  floatx4 oacc[5] = {};
  for (int kc=0;kc<8;kc++){
    __syncthreads();
    {
      const char* kcb = (const char*)(qkv + (size_t)(bt*1024 + kc*128)*3456 + 1152 + hh*72);
#pragma unroll
      for (int i=0;i<6;i++){
        const int u = (wave*6+i)*64 + lane;      // 0..1535
        const int row = u/12;
        const int pp = u - row*12;
        const int c = (pp & 12) | ((pp & 3) ^ (row & 3));
        const void* src = (c<9) ? (const void*)(kcb + (size_t)row*6912 + c*16)
                                : (const void*)zbuf;
        gl_lds16(src, (char*)Ks + (size_t)(wave*6+i)*1024);
      }
#pragma unroll
      for (int i=0;i<5;i++){
        const int u = (wave*5+i)*64 + lane;      // 0..1279
        const int row = u>>4;
        const int pp = u & 15;
        const int c = (pp & 8) | ((pp & 7) ^ (row & 7));
        gl_lds16((const char*)vg + (size_t)row*2048 + kc*256 + c*16,
                 (char*)Vs + (size_t)(wave*5+i)*1024);
      }
    }
    __syncthreads();
    floatx4 sc[8] = {};
    const int ksw = (quad ^ (l16&3))*8;
#pragma unroll
    for (int ct=0;ct<8;ct++){
      const bf16* kr = Ks + (ct*16+l16)*96 + ksw;
      sc[ct] = __builtin_amdgcn_mfma_f32_16x16x32_bf16(af0, *(const bf16x8*)(kr   ), sc[ct],0,0,0);
      sc[ct] = __builtin_amdgcn_mfma_f32_16x16x32_bf16(af1, *(const bf16x8*)(kr+32), sc[ct],0,0,0);
      sc[ct] = __builtin_amdgcn_mfma_f32_16x16x32_bf16(af2, *(const bf16x8*)(kr+64), sc[ct],0,0,0);
    }
    float cm[4];
#pragma unroll
    for (int r=0;r<4;r++){
      cm[r] = sc[0][r];
#pragma unroll
      for (int ct=1;ct<8;ct++) cm[r] = fmaxf(cm[r], sc[ct][r]);
    }
#pragma unroll
    for (int off=1; off<16; off<<=1)
#pragma unroll
      for (int r=0;r<4;r++) cm[r] = fmaxf(cm[r], __shfl_xor(cm[r], off, 64));
    float al[4], ls[4];
#pragma unroll
    for (int r=0;r<4;r++){
      const float mn = fmaxf(mr[r], cm[r]);
      al[r] = exp2f(mr[r]-mn);
      mr[r] = mn; ls[r] = 0.f;
    }
#pragma unroll
    for (int ct=0;ct<8;ct++){
#pragma unroll
      for (int r=0;r<4;r++){
        const float pv = exp2f(sc[ct][r]-mr[r]);
        ls[r] += pv;
        const int row = wave*16+quad*4+r;
        const int c = ct*2 + (l16>>3);
        const int pp = (c & 8) | ((c & 7) ^ (row & 7));
        Ps[row*128 + pp*8 + (l16&7)] = __float2bfloat16(pv);
      }
    }
#pragma unroll
    for (int off=1; off<16; off<<=1)
#pragma unroll
      for (int r=0;r<4;r++) ls[r] += __shfl_xor(ls[r], off, 64);
#pragma unroll
    for (int r=0;r<4;r++) lr[r] = lr[r]*al[r] + ls[r];
#pragma unroll
    for (int t=0;t<5;t++)
#pragma unroll
      for (int r=0;r<4;r++) oacc[t][r] *= al[r];
    __syncthreads();
#pragma unroll
    for (int ks=0;ks<4;ks++){
      const int c = ks*4 + quad;
      const int pp = (c & 8) | ((c & 7) ^ (l16 & 7));
      const bf16x8 pf = *(const bf16x8*)(Ps + (wave*16+l16)*128 + pp*8);
#pragma unroll
      for (int t=0;t<5;t++){
        const bf16x8 vf = *(const bf16x8*)(Vs + (t*16+l16)*128 + pp*8);
        oacc[t] = __builtin_amdgcn_mfma_f32_16x16x32_bf16(pf, vf, oacc[t],0,0,0);
      }
    }
  }
#pragma unroll
  for (int t=0;t<5;t++){
    const int dh = t*16+l16;
    if (dh < 72){
#pragma unroll
      for (int r=0;r<4;r++){
        const int q = wave*16 + quad*4 + r;
        const float v = oacc[t][r] / lr[r];
        outp[((size_t)bt*1024 + q0 + q)*1152 + hh*72 + dh] = __float2bfloat16(v);
      }
    }
  }
}

extern "C" void kernel_launch(void* const* d_in, const int* in_sizes, int n_in,
                              void* d_out, int out_size, void* d_ws, size_t ws_size,
                              hipStream_t stream)
{
  (void)in_sizes; (void)n_in; (void)out_size; (void)ws_size;
  const float* images = (const float*)d_in[0];
  const float* conv_w = (const float*)d_in[1];
  const float* conv_b = (const float*)d_in[2];
  const float* pos_emb= (const float*)d_in[3];
  const float* ln1_g  = (const float*)d_in[4];
  const float* ln1_b  = (const float*)d_in[5];
  const float* Wq     = (const float*)d_in[6];
  const float* bq     = (const float*)d_in[7];
  const float* Wk     = (const float*)d_in[8];
  const float* bk     = (const float*)d_in[9];
  const float* Wv     = (const float*)d_in[10];
  const float* bv     = (const float*)d_in[11];
  const float* Wo     = (const float*)d_in[12];
  const float* bo     = (const float*)d_in[13];
  const float* ln2_g  = (const float*)d_in[14];
  const float* ln2_b  = (const float*)d_in[15];
  const float* W1     = (const float*)d_in[16];
  const float* b1     = (const float*)d_in[17];
  const float* W2     = (const float*)d_in[18];
  const float* b2     = (const float*)d_in[19];
  const float* lnf_g  = (const float*)d_in[20];
  const float* lnf_b  = (const float*)d_in[21];

  char* p = (char*)d_ws;
  auto take = [&](size_t nbytes)->char*{ char* q = p; p += (nbytes + 255) & ~(size_t)255; return q; };
  float* xw   = (float*)take(4096ull*1152*4);
  bf16* hbuf  = (bf16*) take(4096ull*1152*2);
  bf16* h1    = (bf16*) take(4096ull*4352*2);
  bf16* qkvr  = h1;
  bf16* vbuf  = (bf16*) take(64ull*80*1024*2);
  bf16* imcol = vbuf;
  bf16* aout  = (bf16*) take(4096ull*1152*2);
  bf16* WqkvT = (bf16*) take(3456ull*1152*2);
  bf16* WoT   = (bf16*) take(1152ull*1152*2);
  bf16* W1T   = (bf16*) take(4352ull*1152*2);
  bf16* cwT   = W1T;
  bf16* W2T   = (bf16*) take(1152ull*4352*2);
  bf16* Ppart = (bf16*) take(4ull*4096*1152*2);  // bf16 split-K partials (max ks=4)
  float* bqkv = (float*)take(3456*4);
  float* b1p  = (float*)take(4352*4);
  float4* zbuf= (float4*)take(256);

  const float qscale = 1.4426950408889634f / sqrtf(72.0f);

  im2col_kernel<<<9728, 256, 0, stream>>>(images, imcol);
  transpose_cvt<<<dim3(36,19), 256, 0, stream>>>(conv_w, cwT, 588, 1152, 608, 1152);
  gemm_bf16<4><<<dim3(9,32,2), 256, 0, stream>>>(imcol, cwT, conv_b, Ppart, 1152, 608, 320, 0.f);

  for (int l=0;l<4;l++){
    transpose_cvt<<<dim3(36,36), 256, 0, stream>>>(Wq + (size_t)l*1152*1152, WqkvT,                1152,1152,1152,1152);
    transpose_cvt<<<dim3(36,36), 256, 0, stream>>>(Wk + (size_t)l*1152*1152, WqkvT + 1152ull*1152, 1152,1152,1152,1152);
    transpose_cvt<<<dim3(36,36), 256, 0, stream>>>(Wv + (size_t)l*1152*1152, WqkvT + 2304ull*1152, 1152,1152,1152,1152);
    transpose_cvt<<<dim3(36,36), 256, 0, stream>>>(Wo + (size_t)l*1152*1152, WoT, 1152,1152,1152,1152);
    transpose_cvt<<<dim3(136,36),256, 0, stream>>>(W1 + (size_t)l*1152*4304, W1T, 1152,4304,1152,4352);
    transpose_cvt<<<dim3(36,136),256, 0, stream>>>(W2 + (size_t)l*4304*1152, W2T, 4304,1152,4352,1152);
    pack_biases<<<17,256,0,stream>>>(bq,bk,bv,b1,l,bqkv,b1p,zbuf);

    if (l==0)
      ln_red<0,1><<<1024,256,0,stream>>>(pos_emb, 1023u, Ppart, 2, ln1_g, ln1_b, xw, hbuf);
    else
      ln_red<0,1><<<1024,256,0,stream>>>(xw, 4095u, Ppart, 4, ln1_g + l*1152, ln1_b + l*1152, xw, hbuf);

    gemm_bf16<3><<<dim3(27,32,1),256,0,stream>>>(hbuf, WqkvT, bqkv, qkvr, 3456, 1152, 1152, qscale);
    transpose_v<<<dim3(8,64),256,0,stream>>>(qkvr, vbuf);
    attn_kernel<<<dim3(16,64),256,0,stream>>>(qkvr, vbuf, zbuf, aout);
    gemm_bf16<4><<<dim3(9,32,3),256,0,stream>>>(aout, WoT, bo + l*1152, Ppart, 1152, 1152, 384, 0.f);
    ln_red<0,1><<<1024,256,0,stream>>>(xw, 4095u, Ppart, 3, ln2_g + l*1152, ln2_b + l*1152, xw, hbuf);

    gemm_bf16<1><<<dim3(34,32,1),256,0,stream>>>(hbuf, W1T, b1p, h1, 4352, 1152, 1152, 0.f);
    gemm_bf16<4><<<dim3(9,32,4),256,0,stream>>>(h1, W2T, b2 + l*1152, Ppart, 1152, 4352, 1088, 0.f);
  }
  ln_red<1,0><<<1024,256,0,stream>>>(xw, 4095u, Ppart, 4, lnf_g, lnf_b, nullptr, (float*)d_out);
}